// Round 6
// baseline (5070.004 us; speedup 1.0000x reference)
//
#include <hip/hip_runtime.h>
#include <cmath>

typedef unsigned short u16;
typedef unsigned int u32;
typedef unsigned long long u64;
typedef __attribute__((ext_vector_type(8))) short s16x8;
typedef __attribute__((ext_vector_type(8))) unsigned short u16x8;
typedef __attribute__((ext_vector_type(4))) unsigned short u16x4;
typedef __attribute__((ext_vector_type(4))) float f32x4;

#define LN_EPS 1e-6f
#define SCOPE_AGENT __HIP_MEMORY_SCOPE_AGENT

// ---------- helpers ----------
__device__ __forceinline__ u16 f2bf(float f) {
  union { float f; u32 u; } v; v.f = f;
  u32 r = v.u + 0x7FFFu + ((v.u >> 16) & 1u);
  return (u16)(r >> 16);
}
__device__ __forceinline__ float bf2f(u16 h) {
  union { u32 u; float f; } v; v.u = ((u32)h) << 16; return v.f;
}

// agent-scope (MALL-coherent) relaxed accessors — the PROVEN cross-wg path
__device__ __forceinline__ u32 aload32(const u32* p) {
  return __hip_atomic_load(p, __ATOMIC_RELAXED, SCOPE_AGENT);
}
__device__ __forceinline__ void astore32(u32* p, u32 v) {
  __hip_atomic_store(p, v, __ATOMIC_RELAXED, SCOPE_AGENT);
}
__device__ __forceinline__ u64 aload64(const u64* p) {
  return __hip_atomic_load(p, __ATOMIC_RELAXED, SCOPE_AGENT);
}

__device__ __forceinline__ void gload_lds16(const void* g, void* l) {
  __builtin_amdgcn_global_load_lds(
      (__attribute__((address_space(1))) void*)g,
      (__attribute__((address_space(3))) void*)l, 16, 0, 0);
}

__device__ __forceinline__ f32x4 mfma16(s16x8 a, s16x8 b, f32x4 c) {
  return __builtin_amdgcn_mfma_f32_16x16x32_bf16(a, b, c, 0, 0, 0);
}

// machine barrier (64 wgs): flag words spread 128B apart (one line per wg:
// store side contention-free). Poll: 64 lanes read 64 distinct lines in
// parallel, throttled by s_sleep. Same semantics as proven round-2..4 mbar:
// syncthreads drains vmcnt (all data stores MALL-visible) before signal.
__device__ __forceinline__ void mbar(u32* flags, int mach, int slot,
                                     unsigned tgt, bool skip_poll) {
  __syncthreads(); // compiler emits s_waitcnt vmcnt(0) before s_barrier
  if (threadIdx.x == 0) astore32(flags + (((mach << 6) + slot) << 5), tgt);
  if (!skip_poll) {
    if (threadIdx.x < 64) {
      const u32* fp = flags + (((mach << 6) + threadIdx.x) << 5);
      for (;;) {
        unsigned v = aload32(fp);
        if (__all(v >= tgt)) break;
        __builtin_amdgcn_s_sleep(1);
      }
    }
    __syncthreads();
  }
}

// ---------- kernel 1: Xc[m][2048] = bf16(concat(inputo, attn)), m=b*Tc+tc ----------
__global__ __launch_bounds__(256) void cvtx_kernel(const float* __restrict__ inputo,
                                                   const float* __restrict__ attn,
                                                   u16* __restrict__ Xc,
                                                   int t0, int log2Tc) {
  size_t i = ((size_t)blockIdx.x * 256 + threadIdx.x) * 4;
  size_t m = i >> 10, d = i & 1023;
  int tc = (int)(m & ((1u << log2Tc) - 1));
  int b  = (int)(m >> log2Tc);
  size_t src = ((size_t)b * 256 + t0 + tc) * 1024 + d;
  float4 a = *(const float4*)(inputo + src);
  float4 v = *(const float4*)(attn + src);
  u16x4 va = { f2bf(a.x), f2bf(a.y), f2bf(a.z), f2bf(a.w) };
  u16x4 vb = { f2bf(v.x), f2bf(v.y), f2bf(v.z), f2bf(v.w) };
  *(u16x4*)(Xc + m * 2048 + d) = va;
  *(u16x4*)(Xc + m * 2048 + 1024 + d) = vb;
}

// ---------- kernel 2: WT[n][k] = bf16(W[k][n]) ----------
__global__ __launch_bounds__(256) void wtrans_kernel(const float* __restrict__ W,
                                                     u16* __restrict__ WT) {
  __shared__ float tile[32][33];
  int bn = blockIdx.x & 127;
  int bk = blockIdx.x >> 7;
  int n0 = bn * 32, k0 = bk * 32;
  int tx = threadIdx.x & 31, ty = threadIdx.x >> 5;
#pragma unroll
  for (int i = 0; i < 32; i += 8)
    tile[ty + i][tx] = W[(size_t)(k0 + ty + i) * 4096 + n0 + tx];
  __syncthreads();
#pragma unroll
  for (int i = 0; i < 32; i += 8)
    WT[(size_t)(n0 + ty + i) * 3072 + k0 + tx] = f2bf(tile[tx][ty + i]);
}

// ---------- kernel 3: init hx, cx, flags ----------
__global__ __launch_bounds__(256) void init_kernel(const float* __restrict__ init_hx,
                                                   const float* __restrict__ init_cx,
                                                   u16* __restrict__ hx,
                                                   float* __restrict__ cxbuf,
                                                   u32* __restrict__ flags) {
  int i = blockIdx.x * 256 + threadIdx.x;
  if (i < 64 * 1024) {
    hx[i] = f2bf(init_hx[i & 1023]);
    cxbuf[i] = init_cx[i & 1023];
  }
  if (i < 8192) flags[i] = 0;
}

// ---------- kernel 4: Zxc[m][n] = bf16( sum_k Xc[m][k]*WT[n][k] ) ----------
__global__ __launch_bounds__(256) void gemm_zx_kernel(const u16* __restrict__ Xc,
                                                      const u16* __restrict__ WT,
                                                      u16* __restrict__ Zxc,
                                                      int log2nmt) {
  __shared__ u16 As[128 * 64];
  __shared__ u16 Bs[128 * 64];
  const int tid = threadIdx.x, lane = tid & 63, wave = tid >> 6;
  const int nmt_mask = (1 << log2nmt) - 1;
  int mt = blockIdx.x & nmt_mask;
  int nt = blockIdx.x >> log2nmt;
  const size_t m0 = (size_t)mt * 128, n0 = (size_t)nt * 128;
  const int wm = (wave >> 1) * 64, wn = (wave & 1) * 64;
  const int l15 = lane & 15, kg = lane >> 4;
  const int s_r = lane >> 3;
  const int s_c = (lane & 7) * 8;

  f32x4 acc[4][4];
#pragma unroll
  for (int a = 0; a < 4; ++a)
#pragma unroll
    for (int b = 0; b < 4; ++b) acc[a][b] = (f32x4){0.f, 0.f, 0.f, 0.f};

  for (int k0 = 0; k0 < 2048; k0 += 64) {
#pragma unroll
    for (int it = 0; it < 4; ++it) {
      int ch = (wave << 2) + it;
      int row = (ch << 3) + s_r;
      gload_lds16(Xc + (m0 + row) * 2048 + k0 + s_c, (char*)As + (ch << 10));
      gload_lds16(WT + (n0 + row) * 3072 + k0 + s_c, (char*)Bs + (ch << 10));
    }
    __syncthreads();
#pragma unroll
    for (int kk = 0; kk < 2; ++kk) {
      s16x8 af[4], bf[4];
#pragma unroll
      for (int i = 0; i < 4; ++i)
        af[i] = *(const s16x8*)(As + (wm + i * 16 + l15) * 64 + kk * 32 + kg * 8);
#pragma unroll
      for (int i = 0; i < 4; ++i)
        bf[i] = *(const s16x8*)(Bs + (wn + i * 16 + l15) * 64 + kk * 32 + kg * 8);
#pragma unroll
      for (int mi = 0; mi < 4; ++mi)
#pragma unroll
        for (int ni = 0; ni < 4; ++ni)
          acc[mi][ni] = mfma16(af[mi], bf[ni], acc[mi][ni]);
    }
    __syncthreads();
  }
#pragma unroll
  for (int ni = 0; ni < 4; ++ni) {
    size_t n = n0 + wn + ni * 16 + l15;
#pragma unroll
    for (int mi = 0; mi < 4; ++mi) {
#pragma unroll
      for (int j = 0; j < 4; ++j) {
        size_t m = m0 + wm + mi * 16 + (kg << 2) + j;
        Zxc[m * 4096 + n] = f2bf(acc[mi][ni][j]);
      }
    }
  }
}

// ---------- kernel 5: persistent recurrence, 4 machines x 64 wgs x 256 thr ----------
// machine = 16 batch rows; wg = 16 features x 4 gates (64 cols); wave = 1 gate.
// Wh entirely in VGPRs (128/lane). Cross-wg data (hx, gpart, flags) via relaxed
// agent atomics (MALL-coherent, fence-free). Flags spread one line per wg.
__global__ __launch_bounds__(256, 1) void recurrent_kernel(
    const u16* __restrict__ Zxc, const u16* __restrict__ WT,
    const float* __restrict__ inputo, const float* __restrict__ bias,
    const float* __restrict__ ln_w, const float* __restrict__ ln_b,
    float* __restrict__ out, u16* __restrict__ hx, float* __restrict__ cxbuf,
    u32* __restrict__ gpart, u32* __restrict__ flags,
    int t0, int log2Tc) {
  __shared__ __align__(16) u16 hxS[16 * 1024]; // [row][16B slot k8p=k8^(row&7)], 32KB
  __shared__ __align__(16) u16 zxS[16 * 64];   // [row][gate*16+f] linear, 2KB
  __shared__ float zbuf[16][68];
  __shared__ float spart[4][32];
  __shared__ float stot[16][2];

  const int Tc = 1 << log2Tc;
  const int tid = threadIdx.x, lane = tid & 63, wv = tid >> 6;
  const int mach = blockIdx.x >> 6, slot = blockIdx.x & 63;
  const int f0 = slot << 4;
  const int l15 = lane & 15, kg = lane >> 4;
  const int ncol = (wv << 10) + f0 + l15;      // this lane's output col (gate=wv)
  const float lnw = ln_w[ncol], lnb = ln_b[ncol], bz = bias[ncol];

  // ---- Wh B-fragments in VGPRs: Wh[k][ncol] = WT[ncol][2048+k], 32 k-blocks
  s16x8 bfrag[32];
  {
    const u16* bp = WT + (size_t)ncol * 3072 + 2048 + (kg << 3);
#pragma unroll
    for (int kb = 0; kb < 32; ++kb) bfrag[kb] = *(const s16x8*)(bp + (kb << 5));
  }

  // gates-phase role (tid<128): row grow (16), feature pair gfp
  const int grow = tid >> 3, gfp = (tid & 7) << 1;
  const int gb = (mach << 4) + grow;           // global batch row
  const int gd = f0 + gfp;                     // global feature
  float2 cx = {0.f, 0.f};
  if (tid < 128) cx = *(const float2*)(cxbuf + gb * 1024 + gd);

  const u16* hxg = hx + (mach << 14);          // machine's 16x1024 hx block
  u32* gp_my = gpart + (((mach << 6) + slot) << 5);
  const u32* gp_m = gpart + (((size_t)mach << 6) << 5);

  for (int tc = 0; tc < Tc; ++tc) {
    const int t = t0 + tc;
    const unsigned tgt1 = 2u * (unsigned)t + 1u, tgt2 = tgt1 + 1u;

    // ---- stage hx -> hxS (coherent 8B loads + ds_write_b64), swizzled so
    // GEMM A-frag ds_read_b128 (row stride 2KB) stays conflict-free
#pragma unroll
    for (int it = 0; it < 16; ++it) {
      int s = (it << 8) + tid;                 // u64 slot 0..4095
      int c = s >> 1, h = s & 1;
      int row = c >> 7, k8 = (c & 127) ^ (row & 7);
      u64 v = aload64((const u64*)(hxg + (row << 10) + (k8 << 3) + (h << 2)));
      ((u64*)hxS)[s] = v;
    }
    // ---- stage Zx slice (16 rows x 64 cols bf16): tid<128, wave-linear dest
    if (tid < 128) {
      int row = tid >> 3, q = tid & 7, gate = q >> 1, h = q & 1;
      size_t m = ((size_t)((mach << 4) + row) << log2Tc) + tc;
      gload_lds16(Zxc + m * 4096 + ((size_t)gate << 10) + f0 + (h << 3),
                  (char*)zxS + (tid << 4));
    }
    float2 inv = {0.f, 0.f};
    if (tid < 128) inv = *(const float2*)(inputo + ((size_t)gb * 256 + t) * 1024 + gd);
    __syncthreads(); // drains loads, LDS visible

    // ---- GEMM: 16 rows x 16 cols per wave, K=1024 split into 2 indep chains
    f32x4 aca = (f32x4){0.f, 0.f, 0.f, 0.f};
    f32x4 acb = (f32x4){0.f, 0.f, 0.f, 0.f};
#pragma unroll
    for (int kb = 0; kb < 16; ++kb) {
      int k8a = (kb << 2) | kg;
      int k8b = ((kb + 16) << 2) | kg;
      s16x8 a0 = *(const s16x8*)(hxS + (l15 << 10) + ((k8a ^ (l15 & 7)) << 3));
      s16x8 a1 = *(const s16x8*)(hxS + (l15 << 10) + ((k8b ^ (l15 & 7)) << 3));
      aca = mfma16(a0, bfrag[kb], aca);
      acb = mfma16(a1, bfrag[kb + 16], acb);
    }

    // ---- z = acc + zx + bias; per-row partial stats over this wave's 16 cols
    float z[4], s1[4], s2[4];
#pragma unroll
    for (int j = 0; j < 4; ++j) {
      int row = (kg << 2) + j;
      float zx = bf2f(zxS[(row << 6) + (wv << 4) + l15]);
      z[j] = (aca[j] + acb[j]) + zx + bz;
      s1[j] = z[j];
      s2[j] = z[j] * z[j];
    }
#pragma unroll
    for (int off = 1; off < 16; off <<= 1) {
#pragma unroll
      for (int j = 0; j < 4; ++j) {
        s1[j] += __shfl_xor(s1[j], off, 64);
        s2[j] += __shfl_xor(s2[j], off, 64);
      }
    }
    if (l15 == 0) {
#pragma unroll
      for (int j = 0; j < 4; ++j) {
        int row = (kg << 2) + j;
        spart[wv][(row << 1) + 0] = s1[j];
        spart[wv][(row << 1) + 1] = s2[j];
      }
    }
    __syncthreads();
    if (tid < 32) { // tid = (row<<1)|kind; one coalesced line per wg
      float sv = spart[0][tid] + spart[1][tid] + spart[2][tid] + spart[3][tid];
      astore32(gp_my + tid, __float_as_uint(sv));
    }
    mbar(flags, mach, slot, tgt1, false); // stats partials visible

    // ---- reduce 32 targets x 64 slots: lane = (half,target); per-q instruction
    // 32 lanes read one full 128B line (coalesced), 32 lines per half, pipelined
    if (tid < 64) {
      int tg = tid & 31, hf = tid >> 5;
      float s = 0.f;
#pragma unroll 16
      for (int q = 0; q < 32; ++q)
        s += __uint_as_float(aload32(gp_m + (((hf << 5) + q) << 5) + tg));
      s += __shfl_xor(s, 32, 64);
      if (hf == 0) stot[tg >> 1][tg & 1] = s;
    }
    __syncthreads();

    // ---- LN -> zbuf
#pragma unroll
    for (int j = 0; j < 4; ++j) {
      int row = (kg << 2) + j;
      float mean = stot[row][0] * (1.f / 4096.f);
      float var = stot[row][1] * (1.f / 4096.f) - mean * mean;
      float rstd = 1.f / sqrtf(var + LN_EPS);
      zbuf[row][(wv << 4) + l15] = (z[j] - mean) * rstd * lnw + lnb;
    }
    __syncthreads();

    // ---- gates + state update (tid<128: 1 row x 2 features)
    if (tid < 128) {
      float2 zi = *(const float2*)&zbuf[grow][gfp];
      float2 zf = *(const float2*)&zbuf[grow][16 + gfp];
      float2 zo = *(const float2*)&zbuf[grow][32 + gfp];
      float2 zh = *(const float2*)&zbuf[grow][48 + gfp];
      float ig0 = 1.f / (1.f + expf(-zi.x)), ig1 = 1.f / (1.f + expf(-zi.y));
      float fg0 = 1.f / (1.f + expf(-zf.x)), fg1 = 1.f / (1.f + expf(-zf.y));
      float og0 = 1.f / (1.f + expf(-zo.x)), og1 = 1.f / (1.f + expf(-zo.y));
      float h0 = 0.5f * zh.x * (1.f + erff(zh.x * 0.70710678118654752f));
      float h1 = 0.5f * zh.y * (1.f + erff(zh.y * 0.70710678118654752f));
      cx.x = fg0 * cx.x + ig0 * h0;
      cx.y = fg1 * cx.y + ig1 * h1;
      float hx0 = og0 * cx.x, hx1 = og1 * cx.y;
      float2 ov = { hx0 + inv.x, hx1 + inv.y };
      *(float2*)(out + ((size_t)gb * 256 + t) * 1024 + gd) = ov;
      u32 hpack = (u32)f2bf(hx0) | ((u32)f2bf(hx1) << 16);
      astore32((u32*)(hx + gb * 1024 + gd), hpack);
    }
    mbar(flags, mach, slot, tgt2, tc == Tc - 1); // hx(t) visible
  }
  if (tid < 128) *(float2*)(cxbuf + gb * 1024 + gd) = cx;
}

// ---------- launch ----------
extern "C" void kernel_launch(void* const* d_in, const int* in_sizes, int n_in,
                              void* d_out, int out_size, void* d_ws, size_t ws_size,
                              hipStream_t stream) {
  const float* inputo  = (const float*)d_in[0];
  const float* attn    = (const float*)d_in[1];
  const float* W       = (const float*)d_in[2];
  const float* bias    = (const float*)d_in[3];
  const float* ln_w    = (const float*)d_in[4];
  const float* ln_b    = (const float*)d_in[5];
  const float* init_hx = (const float*)d_in[6];
  const float* init_cx = (const float*)d_in[7];
  float* out = (float*)d_out;

  const size_t WT_BYTES = (size_t)4096 * 3072 * 2;            // 24 MiB
  const size_t TAIL = 131072 + 262144 + 32768 + 32768;        // hx, cx, gpart, flags
  int log2Tc = 7;
  for (; log2Tc > 2; --log2Tc) {
    size_t Tc = (size_t)1 << log2Tc;
    size_t need = WT_BYTES + Tc * 262144 /*Xc*/ + Tc * 524288 /*Zxc*/ + TAIL;
    if (need <= ws_size) break;
  }
  const int Tc = 1 << log2Tc;
  const int nchunks = 256 / Tc;

  char* ws = (char*)d_ws;
  size_t off = 0;
  u16* WT       = (u16*)(ws + off); off += WT_BYTES;
  u16* Xc       = (u16*)(ws + off); off += (size_t)Tc * 262144;
  u16* Zxc      = (u16*)(ws + off); off += (size_t)Tc * 524288;
  u16* hx       = (u16*)(ws + off); off += 131072;
  float* cxbuf  = (float*)(ws + off); off += 262144;
  u32* gpart    = (u32*)(ws + off); off += 32768;
  u32* flg      = (u32*)(ws + off);

  wtrans_kernel<<<12288, 256, 0, stream>>>(W, WT);
  init_kernel<<<256, 256, 0, stream>>>(init_hx, init_cx, hx, cxbuf, flg);

  for (int c = 0; c < nchunks; ++c) {
    int t0 = c * Tc;
    cvtx_kernel<<<64 * Tc, 256, 0, stream>>>(inputo, attn, Xc, t0, log2Tc);
    gemm_zx_kernel<<<(Tc / 2) * 32, 256, 0, stream>>>(Xc, WT, Zxc, log2Tc - 1);
    recurrent_kernel<<<256, 256, 0, stream>>>(Zxc, WT, inputo, bias, ln_w, ln_b,
                                              out, hx, cxbuf, gpart, flg,
                                              t0, log2Tc);
  }
}

// Round 7
// 2174.218 us; speedup vs baseline: 2.3319x; 2.3319x over previous
//
#include <hip/hip_runtime.h>
#include <cmath>

typedef unsigned short u16;
typedef unsigned int u32;
typedef unsigned long long u64;
typedef __attribute__((ext_vector_type(8))) short s16x8;
typedef __attribute__((ext_vector_type(8))) unsigned short u16x8;
typedef __attribute__((ext_vector_type(4))) unsigned short u16x4;
typedef __attribute__((ext_vector_type(4))) float f32x4;

#define LN_EPS 1e-6f
#define SCOPE_AGENT __HIP_MEMORY_SCOPE_AGENT

// ---------- helpers ----------
__device__ __forceinline__ u16 f2bf(float f) {
  union { float f; u32 u; } v; v.f = f;
  u32 r = v.u + 0x7FFFu + ((v.u >> 16) & 1u);
  return (u16)(r >> 16);
}
__device__ __forceinline__ float bf2f(u16 h) {
  union { u32 u; float f; } v; v.u = ((u32)h) << 16; return v.f;
}

// agent-scope (MALL-coherent) relaxed accessors — the PROVEN cross-wg path
__device__ __forceinline__ u32 aload32(const u32* p) {
  return __hip_atomic_load(p, __ATOMIC_RELAXED, SCOPE_AGENT);
}
__device__ __forceinline__ void astore32(u32* p, u32 v) {
  __hip_atomic_store(p, v, __ATOMIC_RELAXED, SCOPE_AGENT);
}

// batched coherent loads: 8 x dwordx4 issued back-to-back (forced MLP),
// single vmcnt(0). sc0 sc1 = bypass L1+L2, served by MALL (>= atomic-load
// bypass strength, so remote agent-relaxed stores are visible).
__device__ __forceinline__ void ld128x8_coh(const void* p0, const void* p1,
                                            const void* p2, const void* p3,
                                            const void* p4, const void* p5,
                                            const void* p6, const void* p7,
                                            f32x4& a, f32x4& b, f32x4& c, f32x4& d,
                                            f32x4& e, f32x4& f, f32x4& g, f32x4& h) {
  asm volatile(
      "global_load_dwordx4 %0, %8, off sc0 sc1\n\t"
      "global_load_dwordx4 %1, %9, off sc0 sc1\n\t"
      "global_load_dwordx4 %2, %10, off sc0 sc1\n\t"
      "global_load_dwordx4 %3, %11, off sc0 sc1\n\t"
      "global_load_dwordx4 %4, %12, off sc0 sc1\n\t"
      "global_load_dwordx4 %5, %13, off sc0 sc1\n\t"
      "global_load_dwordx4 %6, %14, off sc0 sc1\n\t"
      "global_load_dwordx4 %7, %15, off sc0 sc1\n\t"
      "s_waitcnt vmcnt(0)"
      : "=&v"(a), "=&v"(b), "=&v"(c), "=&v"(d),
        "=&v"(e), "=&v"(f), "=&v"(g), "=&v"(h)
      : "v"(p0), "v"(p1), "v"(p2), "v"(p3),
        "v"(p4), "v"(p5), "v"(p6), "v"(p7)
      : "memory");
}

__device__ __forceinline__ void gload_lds16(const void* g, void* l) {
  __builtin_amdgcn_global_load_lds(
      (__attribute__((address_space(1))) void*)g,
      (__attribute__((address_space(3))) void*)l, 16, 0, 0);
}

__device__ __forceinline__ f32x4 mfma16(s16x8 a, s16x8 b, f32x4 c) {
  return __builtin_amdgcn_mfma_f32_16x16x32_bf16(a, b, c, 0, 0, 0);
}

// machine barrier (64 wgs): flag words spread one 128B line per wg; store is
// contention-free; 64 lanes poll 64 distinct lines, throttled by s_sleep.
// Semantics proven rounds 2/3/4/6.
__device__ __forceinline__ void mbar(u32* flags, int mach, int slot,
                                     unsigned tgt, bool skip_poll) {
  __syncthreads(); // compiler emits s_waitcnt vmcnt(0) before s_barrier
  if (threadIdx.x == 0) astore32(flags + (((mach << 6) + slot) << 5), tgt);
  if (!skip_poll) {
    if (threadIdx.x < 64) {
      const u32* fp = flags + (((mach << 6) + threadIdx.x) << 5);
      for (;;) {
        unsigned v = aload32(fp);
        if (__all(v >= tgt)) break;
        __builtin_amdgcn_s_sleep(1);
      }
    }
    __syncthreads();
  }
}

// ---------- kernel 1: Xc[m][2048] = bf16(concat(inputo, attn)), m=b*Tc+tc ----------
__global__ __launch_bounds__(256) void cvtx_kernel(const float* __restrict__ inputo,
                                                   const float* __restrict__ attn,
                                                   u16* __restrict__ Xc,
                                                   int t0, int log2Tc) {
  size_t i = ((size_t)blockIdx.x * 256 + threadIdx.x) * 4;
  size_t m = i >> 10, d = i & 1023;
  int tc = (int)(m & ((1u << log2Tc) - 1));
  int b  = (int)(m >> log2Tc);
  size_t src = ((size_t)b * 256 + t0 + tc) * 1024 + d;
  float4 a = *(const float4*)(inputo + src);
  float4 v = *(const float4*)(attn + src);
  u16x4 va = { f2bf(a.x), f2bf(a.y), f2bf(a.z), f2bf(a.w) };
  u16x4 vb = { f2bf(v.x), f2bf(v.y), f2bf(v.z), f2bf(v.w) };
  *(u16x4*)(Xc + m * 2048 + d) = va;
  *(u16x4*)(Xc + m * 2048 + 1024 + d) = vb;
}

// ---------- kernel 2: WT[n][k] = bf16(W[k][n]) ----------
__global__ __launch_bounds__(256) void wtrans_kernel(const float* __restrict__ W,
                                                     u16* __restrict__ WT) {
  __shared__ float tile[32][33];
  int bn = blockIdx.x & 127;
  int bk = blockIdx.x >> 7;
  int n0 = bn * 32, k0 = bk * 32;
  int tx = threadIdx.x & 31, ty = threadIdx.x >> 5;
#pragma unroll
  for (int i = 0; i < 32; i += 8)
    tile[ty + i][tx] = W[(size_t)(k0 + ty + i) * 4096 + n0 + tx];
  __syncthreads();
#pragma unroll
  for (int i = 0; i < 32; i += 8)
    WT[(size_t)(n0 + ty + i) * 3072 + k0 + tx] = f2bf(tile[tx][ty + i]);
}

// ---------- kernel 3: init hx, cx, flags ----------
__global__ __launch_bounds__(256) void init_kernel(const float* __restrict__ init_hx,
                                                   const float* __restrict__ init_cx,
                                                   u16* __restrict__ hx,
                                                   float* __restrict__ cxbuf,
                                                   u32* __restrict__ flags) {
  int i = blockIdx.x * 256 + threadIdx.x;
  if (i < 64 * 1024) {
    hx[i] = f2bf(init_hx[i & 1023]);
    cxbuf[i] = init_cx[i & 1023];
  }
  if (i < 8192) flags[i] = 0;
}

// ---------- kernel 4: Zxc[m][n] = bf16( sum_k Xc[m][k]*WT[n][k] ) ----------
__global__ __launch_bounds__(256) void gemm_zx_kernel(const u16* __restrict__ Xc,
                                                      const u16* __restrict__ WT,
                                                      u16* __restrict__ Zxc,
                                                      int log2nmt) {
  __shared__ u16 As[128 * 64];
  __shared__ u16 Bs[128 * 64];
  const int tid = threadIdx.x, lane = tid & 63, wave = tid >> 6;
  const int nmt_mask = (1 << log2nmt) - 1;
  int mt = blockIdx.x & nmt_mask;
  int nt = blockIdx.x >> log2nmt;
  const size_t m0 = (size_t)mt * 128, n0 = (size_t)nt * 128;
  const int wm = (wave >> 1) * 64, wn = (wave & 1) * 64;
  const int l15 = lane & 15, kg = lane >> 4;
  const int s_r = lane >> 3;
  const int s_c = (lane & 7) * 8;

  f32x4 acc[4][4];
#pragma unroll
  for (int a = 0; a < 4; ++a)
#pragma unroll
    for (int b = 0; b < 4; ++b) acc[a][b] = (f32x4){0.f, 0.f, 0.f, 0.f};

  for (int k0 = 0; k0 < 2048; k0 += 64) {
#pragma unroll
    for (int it = 0; it < 4; ++it) {
      int ch = (wave << 2) + it;
      int row = (ch << 3) + s_r;
      gload_lds16(Xc + (m0 + row) * 2048 + k0 + s_c, (char*)As + (ch << 10));
      gload_lds16(WT + (n0 + row) * 3072 + k0 + s_c, (char*)Bs + (ch << 10));
    }
    __syncthreads();
#pragma unroll
    for (int kk = 0; kk < 2; ++kk) {
      s16x8 af[4], bf[4];
#pragma unroll
      for (int i = 0; i < 4; ++i)
        af[i] = *(const s16x8*)(As + (wm + i * 16 + l15) * 64 + kk * 32 + kg * 8);
#pragma unroll
      for (int i = 0; i < 4; ++i)
        bf[i] = *(const s16x8*)(Bs + (wn + i * 16 + l15) * 64 + kk * 32 + kg * 8);
#pragma unroll
      for (int mi = 0; mi < 4; ++mi)
#pragma unroll
        for (int ni = 0; ni < 4; ++ni)
          acc[mi][ni] = mfma16(af[mi], bf[ni], acc[mi][ni]);
    }
    __syncthreads();
  }
#pragma unroll
  for (int ni = 0; ni < 4; ++ni) {
    size_t n = n0 + wn + ni * 16 + l15;
#pragma unroll
    for (int mi = 0; mi < 4; ++mi) {
#pragma unroll
      for (int j = 0; j < 4; ++j) {
        size_t m = m0 + wm + mi * 16 + (kg << 2) + j;
        Zxc[m * 4096 + n] = f2bf(acc[mi][ni][j]);
      }
    }
  }
}

// ---------- kernel 5: persistent recurrence, 4 machines x 64 wgs x 256 thr ----------
// machine = 16 batch rows; wg = 16 features x 4 gates (64 cols); wave = 1 gate.
// Wh entirely in VGPRs (128/lane). Cross-wg data (hx, gpart, flags) via
// MALL-coherent path; latency-critical reads batched via inline-asm MLP.
__global__ __launch_bounds__(256, 1) void recurrent_kernel(
    const u16* __restrict__ Zxc, const u16* __restrict__ WT,
    const float* __restrict__ inputo, const float* __restrict__ bias,
    const float* __restrict__ ln_w, const float* __restrict__ ln_b,
    float* __restrict__ out, u16* __restrict__ hx, float* __restrict__ cxbuf,
    u32* __restrict__ gpart, u32* __restrict__ flags,
    int t0, int log2Tc) {
  __shared__ __align__(16) u16 hxS[16 * 1024]; // [row][16B slot k8p=k8^(row&7)], 32KB
  __shared__ __align__(16) u16 zxS[16 * 64];   // [row][gate*16+f] linear, 2KB
  __shared__ float zbuf[16][68];
  __shared__ float spart[4][32];
  __shared__ float stot[16][2];

  const int Tc = 1 << log2Tc;
  const int tid = threadIdx.x, lane = tid & 63, wv = tid >> 6;
  const int mach = blockIdx.x >> 6, slot = blockIdx.x & 63;
  const int f0 = slot << 4;
  const int l15 = lane & 15, kg = lane >> 4;
  const int ncol = (wv << 10) + f0 + l15;      // this lane's output col (gate=wv)
  const float lnw = ln_w[ncol], lnb = ln_b[ncol], bz = bias[ncol];

  // ---- Wh B-fragments in VGPRs: Wh[k][ncol] = WT[ncol][2048+k], 32 k-blocks
  s16x8 bfrag[32];
  {
    const u16* bp = WT + (size_t)ncol * 3072 + 2048 + (kg << 3);
#pragma unroll
    for (int kb = 0; kb < 32; ++kb) bfrag[kb] = *(const s16x8*)(bp + (kb << 5));
  }

  // gates-phase role (tid<128): row grow (16), feature pair gfp
  const int grow = tid >> 3, gfp = (tid & 7) << 1;
  const int gb = (mach << 4) + grow;           // global batch row
  const int gd = f0 + gfp;                     // global feature
  float2 cx = {0.f, 0.f};
  if (tid < 128) cx = *(const float2*)(cxbuf + gb * 1024 + gd);

  const u16* hxg = hx + (mach << 14);          // machine's 16x1024 hx block

  // hx-stage addresses (8 x 16B chunks per thread), fixed per thread
  const u16* hp[8];
  int hc[8];
#pragma unroll
  for (int it = 0; it < 8; ++it) {
    int c = (it << 8) + tid;                   // 16B chunk 0..2047
    int row = c >> 7, k8 = (c & 127) ^ (row & 7);
    hp[it] = hxg + (row << 10) + (k8 << 3);
    hc[it] = c;
  }
  // stats-reduce addresses (tid<64): tg=tid>>1 (= (row<<1)|kind), h=tid&1
  const u32* rp = gpart + (mach << 11) + ((tid >> 1) << 6) + ((tid & 1) << 5);
  u32* gp_my = gpart + (mach << 11) + slot;    // writer: [mach][tg][slot]

  for (int tc = 0; tc < Tc; ++tc) {
    const int t = t0 + tc;
    const unsigned tgt1 = 2u * (unsigned)t + 1u, tgt2 = tgt1 + 1u;

    // ---- stage Zx slice (16 rows x 64 cols bf16): tid<128, wave-linear dest
    if (tid < 128) {
      int row = tid >> 3, q = tid & 7, gate = q >> 1, hh = q & 1;
      size_t m = ((size_t)((mach << 4) + row) << log2Tc) + tc;
      gload_lds16(Zxc + m * 4096 + ((size_t)gate << 10) + f0 + (hh << 3),
                  (char*)zxS + (tid << 4));
    }
    // ---- stage hx -> hxS: 8 coherent dwordx4 in flight (1 MALL RTT), then LDS
    {
      f32x4 v0, v1, v2, v3, v4, v5, v6, v7;
      ld128x8_coh(hp[0], hp[1], hp[2], hp[3], hp[4], hp[5], hp[6], hp[7],
                  v0, v1, v2, v3, v4, v5, v6, v7);
      *(f32x4*)(hxS + (hc[0] << 3)) = v0;
      *(f32x4*)(hxS + (hc[1] << 3)) = v1;
      *(f32x4*)(hxS + (hc[2] << 3)) = v2;
      *(f32x4*)(hxS + (hc[3] << 3)) = v3;
      *(f32x4*)(hxS + (hc[4] << 3)) = v4;
      *(f32x4*)(hxS + (hc[5] << 3)) = v5;
      *(f32x4*)(hxS + (hc[6] << 3)) = v6;
      *(f32x4*)(hxS + (hc[7] << 3)) = v7;
    }
    float2 inv = {0.f, 0.f};
    if (tid < 128) inv = *(const float2*)(inputo + ((size_t)gb * 256 + t) * 1024 + gd);
    __syncthreads(); // drains gload_lds, LDS visible

    // ---- GEMM: 16 rows x 16 cols per wave, K=1024, 2 independent chains
    f32x4 aca = (f32x4){0.f, 0.f, 0.f, 0.f};
    f32x4 acb = (f32x4){0.f, 0.f, 0.f, 0.f};
#pragma unroll
    for (int kb = 0; kb < 16; ++kb) {
      int k8a = (kb << 2) | kg;
      int k8b = ((kb + 16) << 2) | kg;
      s16x8 a0 = *(const s16x8*)(hxS + (l15 << 10) + ((k8a ^ (l15 & 7)) << 3));
      s16x8 a1 = *(const s16x8*)(hxS + (l15 << 10) + ((k8b ^ (l15 & 7)) << 3));
      aca = mfma16(a0, bfrag[kb], aca);
      acb = mfma16(a1, bfrag[kb + 16], acb);
    }

    // ---- z = acc + zx + bias; per-row partial stats over this wave's 16 cols
    float z[4], s1[4], s2[4];
#pragma unroll
    for (int j = 0; j < 4; ++j) {
      int row = (kg << 2) + j;
      float zx = bf2f(zxS[(row << 6) + (wv << 4) + l15]);
      z[j] = (aca[j] + acb[j]) + zx + bz;
      s1[j] = z[j];
      s2[j] = z[j] * z[j];
    }
#pragma unroll
    for (int off = 1; off < 16; off <<= 1) {
#pragma unroll
      for (int j = 0; j < 4; ++j) {
        s1[j] += __shfl_xor(s1[j], off, 64);
        s2[j] += __shfl_xor(s2[j], off, 64);
      }
    }
    if (l15 == 0) {
#pragma unroll
      for (int j = 0; j < 4; ++j) {
        int row = (kg << 2) + j;
        spart[wv][(row << 1) + 0] = s1[j];
        spart[wv][(row << 1) + 1] = s2[j];
      }
    }
    __syncthreads();
    if (tid < 32) { // tid = target (row<<1)|kind; scattered async stores
      float sv = spart[0][tid] + spart[1][tid] + spart[2][tid] + spart[3][tid];
      astore32(gp_my + (tid << 6), __float_as_uint(sv));
    }
    mbar(flags, mach, slot, tgt1, false); // stats partials visible

    // ---- reduce 64 slots per target: lane (tg,h) reads 32 contiguous floats
    // in one batched asm block (1 MALL RTT), then 1 shfl
    if (tid < 64) {
      f32x4 v0, v1, v2, v3, v4, v5, v6, v7;
      ld128x8_coh(rp, rp + 4, rp + 8, rp + 12, rp + 16, rp + 20, rp + 24, rp + 28,
                  v0, v1, v2, v3, v4, v5, v6, v7);
      f32x4 q0 = v0 + v1, q1 = v2 + v3, q2 = v4 + v5, q3 = v6 + v7;
      f32x4 q = (q0 + q1) + (q2 + q3);
      float s = (q[0] + q[1]) + (q[2] + q[3]);
      s += __shfl_xor(s, 1, 64);
      if ((tid & 1) == 0) {
        int tg = tid >> 1;
        stot[tg >> 1][tg & 1] = s;
      }
    }
    __syncthreads();

    // ---- LN -> zbuf
#pragma unroll
    for (int j = 0; j < 4; ++j) {
      int row = (kg << 2) + j;
      float mean = stot[row][0] * (1.f / 4096.f);
      float var = stot[row][1] * (1.f / 4096.f) - mean * mean;
      float rstd = 1.f / sqrtf(var + LN_EPS);
      zbuf[row][(wv << 4) + l15] = (z[j] - mean) * rstd * lnw + lnb;
    }
    __syncthreads();

    // ---- gates + state update (tid<128: 1 row x 2 features)
    if (tid < 128) {
      float2 zi = *(const float2*)&zbuf[grow][gfp];
      float2 zf = *(const float2*)&zbuf[grow][16 + gfp];
      float2 zo = *(const float2*)&zbuf[grow][32 + gfp];
      float2 zh = *(const float2*)&zbuf[grow][48 + gfp];
      float ig0 = 1.f / (1.f + expf(-zi.x)), ig1 = 1.f / (1.f + expf(-zi.y));
      float fg0 = 1.f / (1.f + expf(-zf.x)), fg1 = 1.f / (1.f + expf(-zf.y));
      float og0 = 1.f / (1.f + expf(-zo.x)), og1 = 1.f / (1.f + expf(-zo.y));
      float h0 = 0.5f * zh.x * (1.f + erff(zh.x * 0.70710678118654752f));
      float h1 = 0.5f * zh.y * (1.f + erff(zh.y * 0.70710678118654752f));
      cx.x = fg0 * cx.x + ig0 * h0;
      cx.y = fg1 * cx.y + ig1 * h1;
      float hx0 = og0 * cx.x, hx1 = og1 * cx.y;
      float2 ov = { hx0 + inv.x, hx1 + inv.y };
      *(float2*)(out + ((size_t)gb * 256 + t) * 1024 + gd) = ov;
      u32 hpack = (u32)f2bf(hx0) | ((u32)f2bf(hx1) << 16);
      astore32((u32*)(hx + gb * 1024 + gd), hpack);
    }
    mbar(flags, mach, slot, tgt2, tc == Tc - 1); // hx(t) visible
  }
  if (tid < 128) *(float2*)(cxbuf + gb * 1024 + gd) = cx;
}

// ---------- launch ----------
extern "C" void kernel_launch(void* const* d_in, const int* in_sizes, int n_in,
                              void* d_out, int out_size, void* d_ws, size_t ws_size,
                              hipStream_t stream) {
  const float* inputo  = (const float*)d_in[0];
  const float* attn    = (const float*)d_in[1];
  const float* W       = (const float*)d_in[2];
  const float* bias    = (const float*)d_in[3];
  const float* ln_w    = (const float*)d_in[4];
  const float* ln_b    = (const float*)d_in[5];
  const float* init_hx = (const float*)d_in[6];
  const float* init_cx = (const float*)d_in[7];
  float* out = (float*)d_out;

  const size_t WT_BYTES = (size_t)4096 * 3072 * 2;            // 24 MiB
  const size_t TAIL = 131072 + 262144 + 32768 + 32768;        // hx, cx, gpart, flags
  int log2Tc = 7;
  for (; log2Tc > 2; --log2Tc) {
    size_t Tc = (size_t)1 << log2Tc;
    size_t need = WT_BYTES + Tc * 262144 /*Xc*/ + Tc * 524288 /*Zxc*/ + TAIL;
    if (need <= ws_size) break;
  }
  const int Tc = 1 << log2Tc;
  const int nchunks = 256 / Tc;

  char* ws = (char*)d_ws;
  size_t off = 0;
  u16* WT       = (u16*)(ws + off); off += WT_BYTES;
  u16* Xc       = (u16*)(ws + off); off += (size_t)Tc * 262144;
  u16* Zxc      = (u16*)(ws + off); off += (size_t)Tc * 524288;
  u16* hx       = (u16*)(ws + off); off += 131072;
  float* cxbuf  = (float*)(ws + off); off += 262144;
  u32* gpart    = (u32*)(ws + off); off += 32768;
  u32* flg      = (u32*)(ws + off);

  wtrans_kernel<<<12288, 256, 0, stream>>>(W, WT);
  init_kernel<<<256, 256, 0, stream>>>(init_hx, init_cx, hx, cxbuf, flg);

  for (int c = 0; c < nchunks; ++c) {
    int t0 = c * Tc;
    cvtx_kernel<<<64 * Tc, 256, 0, stream>>>(inputo, attn, Xc, t0, log2Tc);
    gemm_zx_kernel<<<(Tc / 2) * 32, 256, 0, stream>>>(Xc, WT, Zxc, log2Tc - 1);
    recurrent_kernel<<<256, 256, 0, stream>>>(Zxc, WT, inputo, bias, ln_w, ln_b,
                                              out, hx, cxbuf, gpart, flg,
                                              t0, log2Tc);
  }
}